// Round 1
// baseline (7350.793 us; speedup 1.0000x reference)
//
#include <hip/hip_runtime.h>

#define D 20
#define ACT 5
#define NEG_SLOPE 0.2f

// ---- ordered-uint transform for float atomicMax (handles negatives) ----
__device__ __forceinline__ unsigned f2ord(float f) {
    unsigned u = __float_as_uint(f);
    return (u & 0x80000000u) ? ~u : (u | 0x80000000u);
}
__device__ __forceinline__ float ord2f(unsigned u) {
    return (u & 0x80000000u) ? __uint_as_float(u & 0x7fffffffu)
                             : __uint_as_float(~u);
}

__device__ __forceinline__ float leaky(float x) {
    return x > 0.f ? x : NEG_SLOPE * x;
}

// 1. h1 = x @ gcn_W ; degf = 1 (self loop)
__global__ void k_xw(const float* __restrict__ x, const float* __restrict__ W,
                     float* __restrict__ h1, float* __restrict__ degf, int n) {
    __shared__ float sW[D * D];
    for (int t = threadIdx.x; t < D * D; t += blockDim.x) sW[t] = W[t];
    __syncthreads();
    int i = blockIdx.x * blockDim.x + threadIdx.x;
    if (i >= n) return;
    float xi[D];
#pragma unroll
    for (int k = 0; k < D; ++k) xi[k] = x[(size_t)i * D + k];
#pragma unroll
    for (int d = 0; d < D; ++d) {
        float acc = 0.f;
#pragma unroll
        for (int k = 0; k < D; ++k) acc += xi[k] * sW[k * D + d];
        h1[(size_t)i * D + d] = acc;
    }
    degf[i] = 1.0f;
}

// 2. deg count over real edges
__global__ void k_deg(const int* __restrict__ dst, float* __restrict__ degf, int e) {
    int i = blockIdx.x * blockDim.x + threadIdx.x;
    if (i < e) atomicAdd(&degf[dst[i]], 1.0f);
}

// 3. dinv = rsqrt(deg) (in place); out1 = dinv^2 * h1 (self-loop term)
__global__ void k_selfgcn(const float* __restrict__ h1, float* __restrict__ degf,
                          float* __restrict__ out1, int n) {
    int i = blockIdx.x * blockDim.x + threadIdx.x;
    if (i >= n) return;
    float di = rsqrtf(degf[i]);
    degf[i] = di;
    float c = di * di;
#pragma unroll
    for (int d = 0; d < D; ++d) out1[(size_t)i * D + d] = c * h1[(size_t)i * D + d];
}

// 4. GCN edge scatter: out1[dst] += dinv[src]*dinv[dst]*h1[src]
__global__ void k_gcn_edge(const int* __restrict__ src, const int* __restrict__ dst,
                           const float* __restrict__ dinv, const float* __restrict__ h1,
                           float* __restrict__ out1, int e) {
    int i = blockIdx.x * blockDim.x + threadIdx.x;
    if (i >= e) return;
    int s = src[i], t = dst[i];
    float norm = dinv[s] * dinv[t];
    const float* hs = h1 + (size_t)s * D;
    float* ot = out1 + (size_t)t * D;
#pragma unroll
    for (int d = 0; d < D; ++d) atomicAdd(&ot[d], norm * hs[d]);
}

// 5. GAT node transform: v=relu(out1+gcn_b); h2=v@gat_W; a_s,a_d dots; m init = self-loop e
__global__ void k_gat_node(const float* __restrict__ out1, const float* __restrict__ gcn_b,
                           const float* __restrict__ gat_W, const float* __restrict__ att_s,
                           const float* __restrict__ att_d,
                           float* __restrict__ h2, float* __restrict__ a_s,
                           float* __restrict__ a_d, unsigned* __restrict__ m_ord, int n) {
    __shared__ float sW[D * D], sb[D], sas[D], sad[D];
    for (int t = threadIdx.x; t < D * D; t += blockDim.x) sW[t] = gat_W[t];
    if (threadIdx.x < D) {
        sb[threadIdx.x]  = gcn_b[threadIdx.x];
        sas[threadIdx.x] = att_s[threadIdx.x];
        sad[threadIdx.x] = att_d[threadIdx.x];
    }
    __syncthreads();
    int i = blockIdx.x * blockDim.x + threadIdx.x;
    if (i >= n) return;
    float v[D];
#pragma unroll
    for (int k = 0; k < D; ++k) {
        float t = out1[(size_t)i * D + k] + sb[k];
        v[k] = t > 0.f ? t : 0.f;
    }
    float as_ = 0.f, ad_ = 0.f;
#pragma unroll
    for (int d = 0; d < D; ++d) {
        float acc = 0.f;
#pragma unroll
        for (int k = 0; k < D; ++k) acc += v[k] * sW[k * D + d];
        h2[(size_t)i * D + d] = acc;
        as_ += acc * sas[d];
        ad_ += acc * sad[d];
    }
    a_s[i] = as_;
    a_d[i] = ad_;
    m_ord[i] = f2ord(leaky(as_ + ad_));   // self-loop edge initializes the segment max
}

// 6. GAT segment max over real edges
__global__ void k_gat_max(const int* __restrict__ src, const int* __restrict__ dst,
                          const float* __restrict__ a_s, const float* __restrict__ a_d,
                          unsigned* __restrict__ m_ord, int e) {
    int i = blockIdx.x * blockDim.x + threadIdx.x;
    if (i >= e) return;
    int s = src[i], t = dst[i];
    atomicMax(&m_ord[t], f2ord(leaky(a_s[s] + a_d[t])));
}

// 7. convert max back to float (in place); init denom/numer with self-loop term
__global__ void k_gat_init(const float* __restrict__ a_s, const float* __restrict__ a_d,
                           const float* __restrict__ h2, unsigned* __restrict__ m_ord,
                           float* __restrict__ denom, float* __restrict__ numer, int n) {
    int i = blockIdx.x * blockDim.x + threadIdx.x;
    if (i >= n) return;
    float mf = ord2f(m_ord[i]);
    ((float*)m_ord)[i] = mf;                // reuse buffer as float for edge kernel
    float ex = __expf(leaky(a_s[i] + a_d[i]) - mf);
    denom[i] = ex;
#pragma unroll
    for (int d = 0; d < D; ++d) numer[(size_t)i * D + d] = ex * h2[(size_t)i * D + d];
}

// 8. GAT edge scatter: denom[dst]+=ex; numer[dst]+=ex*h2[src]
__global__ void k_gat_edge(const int* __restrict__ src, const int* __restrict__ dst,
                           const float* __restrict__ a_s, const float* __restrict__ a_d,
                           const float* __restrict__ mf, const float* __restrict__ h2,
                           float* __restrict__ denom, float* __restrict__ numer, int e) {
    int i = blockIdx.x * blockDim.x + threadIdx.x;
    if (i >= e) return;
    int s = src[i], t = dst[i];
    float ex = __expf(leaky(a_s[s] + a_d[t]) - mf[t]);
    atomicAdd(&denom[t], ex);
    const float* hs = h2 + (size_t)s * D;
    float* nt = numer + (size_t)t * D;
#pragma unroll
    for (int d = 0; d < D; ++d) atomicAdd(&nt[d], ex * hs[d]);
}

// 9. readout: g = sum_i relu(numer[i]/denom[i] + gat_b)
__global__ void k_readout(const float* __restrict__ numer, const float* __restrict__ denom,
                          const float* __restrict__ gat_b, float* __restrict__ g, int n) {
    __shared__ float sb[D];
    if (threadIdx.x < D) sb[threadIdx.x] = gat_b[threadIdx.x];
    __syncthreads();
    float acc[D];
#pragma unroll
    for (int d = 0; d < D; ++d) acc[d] = 0.f;
    for (int i = blockIdx.x * blockDim.x + threadIdx.x; i < n;
         i += gridDim.x * blockDim.x) {
        float inv = 1.0f / denom[i];
#pragma unroll
        for (int d = 0; d < D; ++d) {
            float v = numer[(size_t)i * D + d] * inv + sb[d];
            acc[d] += v > 0.f ? v : 0.f;
        }
    }
#pragma unroll
    for (int d = 0; d < D; ++d) {
        float v = acc[d];
        for (int off = 32; off; off >>= 1) v += __shfl_down(v, off);
        if ((threadIdx.x & 63) == 0) atomicAdd(&g[d], v);
    }
}

// 10. dueling head: Q = V + A - mean(A)
__global__ void k_head(const float* __restrict__ g,
                       const float* __restrict__ aW1, const float* __restrict__ ab1,
                       const float* __restrict__ aW2, const float* __restrict__ ab2,
                       const float* __restrict__ vW1, const float* __restrict__ vb1,
                       const float* __restrict__ vW2, const float* __restrict__ vb2,
                       float* __restrict__ out) {
    __shared__ float sg[D], t1[D], t2[D], A[ACT], V, meanA;
    int t = threadIdx.x;
    if (t < D) sg[t] = g[t];
    __syncthreads();
    if (t < D) {
        float a = ab1[t], v = vb1[t];
        for (int k = 0; k < D; ++k) {
            a += sg[k] * aW1[k * D + t];
            v += sg[k] * vW1[k * D + t];
        }
        t1[t] = a > 0.f ? a : 0.f;
        t2[t] = v > 0.f ? v : 0.f;
    }
    __syncthreads();
    if (t < ACT) {
        float a = ab2[t];
        for (int d = 0; d < D; ++d) a += t1[d] * aW2[d * ACT + t];
        A[t] = a;
    }
    if (t == D) {
        float v = vb2[0];
        for (int d = 0; d < D; ++d) v += t2[d] * vW2[d];
        V = v;
    }
    __syncthreads();
    if (t == 0) {
        float s = 0.f;
        for (int j = 0; j < ACT; ++j) s += A[j];
        meanA = s / ACT;
    }
    __syncthreads();
    if (t < ACT) out[t] = V + A[t] - meanA;
}

extern "C" void kernel_launch(void* const* d_in, const int* in_sizes, int n_in,
                              void* d_out, int out_size, void* d_ws, size_t ws_size,
                              hipStream_t stream) {
    const float* x      = (const float*)d_in[0];
    const int*   ei     = (const int*)d_in[1];
    // d_in[2] edge_attr: unused by the reference
    const float* gcn_W  = (const float*)d_in[3];
    const float* gcn_b  = (const float*)d_in[4];
    const float* gat_W  = (const float*)d_in[5];
    const float* att_s  = (const float*)d_in[6];
    const float* att_d  = (const float*)d_in[7];
    const float* gat_b  = (const float*)d_in[8];
    const float* aW1    = (const float*)d_in[9];
    const float* ab1    = (const float*)d_in[10];
    const float* aW2    = (const float*)d_in[11];
    const float* ab2    = (const float*)d_in[12];
    const float* vW1    = (const float*)d_in[13];
    const float* vb1    = (const float*)d_in[14];
    const float* vW2    = (const float*)d_in[15];
    const float* vb2    = (const float*)d_in[16];

    const int n = in_sizes[0] / D;       // 100000
    const int e = in_sizes[1] / 2;       // 3200000
    const int* src = ei;
    const int* dst = ei + e;

    // workspace layout (floats)
    float* ws    = (float*)d_ws;
    float* h1    = ws;                         // N*D
    float* degf  = h1 + (size_t)n * D;         // N   (deg -> dinv, in place)
    float* out1  = degf + n;                   // N*D (GCN agg; reused as numer)
    float* h2    = out1 + (size_t)n * D;       // N*D
    float* a_s   = h2 + (size_t)n * D;         // N
    float* a_d   = a_s + n;                    // N
    unsigned* m_ord = (unsigned*)(a_d + n);    // N (ord-uint -> float, in place)
    float* denom = (float*)(m_ord) + n;        // N
    float* g     = denom + n;                  // D
    float* numer = out1;                       // alias: out1 dead after k_gat_node

    const int B = 256;
    const int nb_n = (n + B - 1) / B;
    const int nb_e = (e + B - 1) / B;

    k_xw<<<nb_n, B, 0, stream>>>(x, gcn_W, h1, degf, n);
    k_deg<<<nb_e, B, 0, stream>>>(dst, degf, e);
    k_selfgcn<<<nb_n, B, 0, stream>>>(h1, degf, out1, n);
    k_gcn_edge<<<nb_e, B, 0, stream>>>(src, dst, degf, h1, out1, e);
    k_gat_node<<<nb_n, B, 0, stream>>>(out1, gcn_b, gat_W, att_s, att_d,
                                       h2, a_s, a_d, m_ord, n);
    k_gat_max<<<nb_e, B, 0, stream>>>(src, dst, a_s, a_d, m_ord, e);
    k_gat_init<<<nb_n, B, 0, stream>>>(a_s, a_d, h2, m_ord, denom, numer, n);
    k_gat_edge<<<nb_e, B, 0, stream>>>(src, dst, a_s, a_d, (const float*)m_ord,
                                       h2, denom, numer, e);
    hipMemsetAsync(g, 0, D * sizeof(float), stream);
    k_readout<<<nb_n, B, 0, stream>>>(numer, denom, gat_b, g, n);
    k_head<<<1, 64, 0, stream>>>(g, aW1, ab1, aW2, ab2, vW1, vb1, vW2, vb2,
                                 (float*)d_out);
}

// Round 2
// 1184.189 us; speedup vs baseline: 6.2074x; 6.2074x over previous
//
#include <hip/hip_runtime.h>

#define D 20
#define ACT 5
#define NEG_SLOPE 0.2f

__device__ __forceinline__ float leaky(float x) {
    return x > 0.f ? x : NEG_SLOPE * x;
}

// ---------------------------------------------------------------------------
// 1. h1 = x @ gcn_W   (weights staged in LDS, float4 row loads/stores)
// ---------------------------------------------------------------------------
__global__ void k_xw(const float* __restrict__ x, const float* __restrict__ W,
                     float* __restrict__ h1, int n) {
    __shared__ float sW[D * D];
    for (int t = threadIdx.x; t < D * D; t += blockDim.x) sW[t] = W[t];
    __syncthreads();
    int i = blockIdx.x * blockDim.x + threadIdx.x;
    if (i >= n) return;
    float xi[D];
    const float4* xr = (const float4*)(x + (size_t)i * D);
#pragma unroll
    for (int q = 0; q < D / 4; ++q) {
        float4 v = xr[q];
        xi[4 * q + 0] = v.x; xi[4 * q + 1] = v.y;
        xi[4 * q + 2] = v.z; xi[4 * q + 3] = v.w;
    }
    float4* hr = (float4*)(h1 + (size_t)i * D);
#pragma unroll
    for (int q = 0; q < D / 4; ++q) {
        float4 o;
        float* op = (float*)&o;
#pragma unroll
        for (int r = 0; r < 4; ++r) {
            int d = 4 * q + r;
            float acc = 0.f;
#pragma unroll
            for (int k = 0; k < D; ++k) acc += xi[k] * sW[k * D + d];
            op[r] = acc;
        }
        hr[q] = o;
    }
}

// ---------------------------------------------------------------------------
// 2. histogram of dst (real in-degree)
// ---------------------------------------------------------------------------
__global__ void k_hist(const int* __restrict__ dst, int* __restrict__ deg, int e) {
    int i = blockIdx.x * blockDim.x + threadIdx.x;
    if (i < e) atomicAdd(&deg[dst[i]], 1);
}

// ---------------------------------------------------------------------------
// 3. single-block exclusive scan -> off, cur; also dinv = rsqrt(deg+1)
// ---------------------------------------------------------------------------
__global__ void k_scan(const int* __restrict__ deg, int* __restrict__ off,
                       int* __restrict__ cur, float* __restrict__ dinv, int n) {
    __shared__ int ssum[256];
    int t = threadIdx.x;
    int chunk = (n + 255) / 256;
    int lo = t * chunk, hi = min(lo + chunk, n);
    int s = 0;
    for (int i = lo; i < hi; ++i) s += deg[i];
    ssum[t] = s;
    __syncthreads();
    if (t == 0) {
        int run = 0;
        for (int k = 0; k < 256; ++k) { int v = ssum[k]; ssum[k] = run; run += v; }
    }
    __syncthreads();
    int run = ssum[t];
    for (int i = lo; i < hi; ++i) {
        off[i] = run; cur[i] = run;
        dinv[i] = rsqrtf((float)(deg[i] + 1));
        run += deg[i];
    }
    if (hi == n) off[n] = run;   // threads past the data also write total: consistent
}

// ---------------------------------------------------------------------------
// 4. scatter edges into CSR-by-dst (order within segment irrelevant)
// ---------------------------------------------------------------------------
__global__ void k_scatter(const int* __restrict__ src, const int* __restrict__ dst,
                          int* __restrict__ cur, int* __restrict__ esrc, int e) {
    int i = blockIdx.x * blockDim.x + threadIdx.x;
    if (i >= e) return;
    int p = atomicAdd(&cur[dst[i]], 1);
    esrc[p] = src[i];
}

// ---------------------------------------------------------------------------
// 5. fused GCN aggregate (gather, no atomics) + relu + GAT node transform
//    writes h2, a_s, a_d only
// ---------------------------------------------------------------------------
__global__ void k_gcn_gat(const int* __restrict__ off, const int* __restrict__ esrc,
                          const float* __restrict__ dinv, const float* __restrict__ h1,
                          const float* __restrict__ gcn_b, const float* __restrict__ gat_W,
                          const float* __restrict__ att_s, const float* __restrict__ att_d,
                          float* __restrict__ h2, float* __restrict__ a_s,
                          float* __restrict__ a_d, int n) {
    __shared__ float sW[D * D], sb[D], sas[D], sad[D];
    for (int t = threadIdx.x; t < D * D; t += blockDim.x) sW[t] = gat_W[t];
    if (threadIdx.x < D) {
        sb[threadIdx.x]  = gcn_b[threadIdx.x];
        sas[threadIdx.x] = att_s[threadIdx.x];
        sad[threadIdx.x] = att_d[threadIdx.x];
    }
    __syncthreads();
    int i = blockIdx.x * blockDim.x + threadIdx.x;
    if (i >= n) return;

    float di = dinv[i];
    float acc[D];
    {   // self-loop term: dinv[i]^2 * h1[i]
        float c = di * di;
        const float4* hr = (const float4*)(h1 + (size_t)i * D);
#pragma unroll
        for (int q = 0; q < D / 4; ++q) {
            float4 v = hr[q];
            acc[4 * q + 0] = c * v.x; acc[4 * q + 1] = c * v.y;
            acc[4 * q + 2] = c * v.z; acc[4 * q + 3] = c * v.w;
        }
    }
    int s0 = off[i], s1 = off[i + 1];
    for (int j = s0; j < s1; ++j) {
        int s = esrc[j];
        float norm = di * dinv[s];
        const float4* hs = (const float4*)(h1 + (size_t)s * D);
#pragma unroll
        for (int q = 0; q < D / 4; ++q) {
            float4 v = hs[q];
            acc[4 * q + 0] += norm * v.x; acc[4 * q + 1] += norm * v.y;
            acc[4 * q + 2] += norm * v.z; acc[4 * q + 3] += norm * v.w;
        }
    }
    float v[D];
#pragma unroll
    for (int k = 0; k < D; ++k) {
        float t = acc[k] + sb[k];
        v[k] = t > 0.f ? t : 0.f;
    }
    float as_ = 0.f, ad_ = 0.f;
    float4* h2r = (float4*)(h2 + (size_t)i * D);
#pragma unroll
    for (int q = 0; q < D / 4; ++q) {
        float4 o;
        float* op = (float*)&o;
#pragma unroll
        for (int r = 0; r < 4; ++r) {
            int d = 4 * q + r;
            float acc2 = 0.f;
#pragma unroll
            for (int k = 0; k < D; ++k) acc2 += v[k] * sW[k * D + d];
            op[r] = acc2;
            as_ += acc2 * sas[d];
            ad_ += acc2 * sad[d];
        }
        h2r[q] = o;
    }
    a_s[i] = as_;
    a_d[i] = ad_;
}

// ---------------------------------------------------------------------------
// 6. GAT softmax-aggregate per node (two passes over CSR edges, no scatter
//    atomics) fused with graph readout (wave-reduced, 20 atomics/wave)
// ---------------------------------------------------------------------------
__global__ void k_gat_agg(const int* __restrict__ off, const int* __restrict__ esrc,
                          const float* __restrict__ a_s, const float* __restrict__ a_d,
                          const float* __restrict__ h2, const float* __restrict__ gat_b,
                          float* __restrict__ g, int n) {
    __shared__ float sb[D];
    if (threadIdx.x < D) sb[threadIdx.x] = gat_b[threadIdx.x];
    __syncthreads();
    int i = blockIdx.x * blockDim.x + threadIdx.x;
    float out[D];
#pragma unroll
    for (int d = 0; d < D; ++d) out[d] = 0.f;

    if (i < n) {
        float ad_i = a_d[i];
        float eself = leaky(a_s[i] + ad_i);
        int s0 = off[i], s1 = off[i + 1];
        float m = eself;
        for (int j = s0; j < s1; ++j)
            m = fmaxf(m, leaky(a_s[esrc[j]] + ad_i));

        float denom = __expf(eself - m);
        float acc[D];
        {
            const float4* hr = (const float4*)(h2 + (size_t)i * D);
#pragma unroll
            for (int q = 0; q < D / 4; ++q) {
                float4 v = hr[q];
                acc[4 * q + 0] = denom * v.x; acc[4 * q + 1] = denom * v.y;
                acc[4 * q + 2] = denom * v.z; acc[4 * q + 3] = denom * v.w;
            }
        }
        for (int j = s0; j < s1; ++j) {
            int s = esrc[j];
            float ex = __expf(leaky(a_s[s] + ad_i) - m);
            denom += ex;
            const float4* hs = (const float4*)(h2 + (size_t)s * D);
#pragma unroll
            for (int q = 0; q < D / 4; ++q) {
                float4 v = hs[q];
                acc[4 * q + 0] += ex * v.x; acc[4 * q + 1] += ex * v.y;
                acc[4 * q + 2] += ex * v.z; acc[4 * q + 3] += ex * v.w;
            }
        }
        float inv = 1.0f / denom;
#pragma unroll
        for (int d = 0; d < D; ++d) {
            float t = acc[d] * inv + sb[d];
            out[d] = t > 0.f ? t : 0.f;
        }
    }
    // wave reduce each channel, one atomicAdd per wave per channel
#pragma unroll
    for (int d = 0; d < D; ++d) {
        float t = out[d];
        for (int o = 32; o; o >>= 1) t += __shfl_down(t, o);
        if ((threadIdx.x & 63) == 0) atomicAdd(&g[d], t);
    }
}

// ---------------------------------------------------------------------------
// 7. dueling head
// ---------------------------------------------------------------------------
__global__ void k_head(const float* __restrict__ g,
                       const float* __restrict__ aW1, const float* __restrict__ ab1,
                       const float* __restrict__ aW2, const float* __restrict__ ab2,
                       const float* __restrict__ vW1, const float* __restrict__ vb1,
                       const float* __restrict__ vW2, const float* __restrict__ vb2,
                       float* __restrict__ out) {
    __shared__ float sg[D], t1[D], t2[D], A[ACT], V, meanA;
    int t = threadIdx.x;
    if (t < D) sg[t] = g[t];
    __syncthreads();
    if (t < D) {
        float a = ab1[t], v = vb1[t];
        for (int k = 0; k < D; ++k) {
            a += sg[k] * aW1[k * D + t];
            v += sg[k] * vW1[k * D + t];
        }
        t1[t] = a > 0.f ? a : 0.f;
        t2[t] = v > 0.f ? v : 0.f;
    }
    __syncthreads();
    if (t < ACT) {
        float a = ab2[t];
        for (int d = 0; d < D; ++d) a += t1[d] * aW2[d * ACT + t];
        A[t] = a;
    }
    if (t == D) {
        float v = vb2[0];
        for (int d = 0; d < D; ++d) v += t2[d] * vW2[d];
        V = v;
    }
    __syncthreads();
    if (t == 0) {
        float s = 0.f;
        for (int j = 0; j < ACT; ++j) s += A[j];
        meanA = s / ACT;
    }
    __syncthreads();
    if (t < ACT) out[t] = V + A[t] - meanA;
}

extern "C" void kernel_launch(void* const* d_in, const int* in_sizes, int n_in,
                              void* d_out, int out_size, void* d_ws, size_t ws_size,
                              hipStream_t stream) {
    const float* x      = (const float*)d_in[0];
    const int*   ei     = (const int*)d_in[1];
    // d_in[2] edge_attr: unused by the reference
    const float* gcn_W  = (const float*)d_in[3];
    const float* gcn_b  = (const float*)d_in[4];
    const float* gat_W  = (const float*)d_in[5];
    const float* att_s  = (const float*)d_in[6];
    const float* att_d  = (const float*)d_in[7];
    const float* gat_b  = (const float*)d_in[8];
    const float* aW1    = (const float*)d_in[9];
    const float* ab1    = (const float*)d_in[10];
    const float* aW2    = (const float*)d_in[11];
    const float* ab2    = (const float*)d_in[12];
    const float* vW1    = (const float*)d_in[13];
    const float* vb1    = (const float*)d_in[14];
    const float* vW2    = (const float*)d_in[15];
    const float* vb2    = (const float*)d_in[16];

    const int n = in_sizes[0] / D;       // 100000
    const int e = in_sizes[1] / 2;       // 3200000
    const int* src = ei;
    const int* dst = ei + e;

    // workspace layout
    float* ws   = (float*)d_ws;
    float* h1   = ws;                          // N*D
    float* h2   = h1 + (size_t)n * D;          // N*D
    float* a_s  = h2 + (size_t)n * D;          // N
    float* a_d  = a_s + n;                     // N
    float* dinv = a_d + n;                     // N
    float* g    = dinv + n;                    // 32 (padded)
    int*   deg  = (int*)(g + 32);              // N
    int*   off  = deg + n;                     // N+1
    int*   cur  = off + n + 1;                 // N
    int*   esrc = cur + n;                     // E

    const int B = 256;
    const int nb_n = (n + B - 1) / B;
    const int nb_e = (e + B - 1) / B;

    hipMemsetAsync(deg, 0, (size_t)n * sizeof(int), stream);
    hipMemsetAsync(g, 0, D * sizeof(float), stream);

    k_xw<<<nb_n, B, 0, stream>>>(x, gcn_W, h1, n);
    k_hist<<<nb_e, B, 0, stream>>>(dst, deg, e);
    k_scan<<<1, 256, 0, stream>>>(deg, off, cur, dinv, n);
    k_scatter<<<nb_e, B, 0, stream>>>(src, dst, cur, esrc, e);
    k_gcn_gat<<<nb_n, B, 0, stream>>>(off, esrc, dinv, h1, gcn_b, gat_W,
                                      att_s, att_d, h2, a_s, a_d, n);
    k_gat_agg<<<nb_n, B, 0, stream>>>(off, esrc, a_s, a_d, h2, gat_b, g, n);
    k_head<<<1, 64, 0, stream>>>(g, aW1, ab1, aW2, ab2, vW1, vb1, vW2, vb2,
                                 (float*)d_out);
}